// Round 8
// baseline (203.090 us; speedup 1.0000x reference)
//
#include <hip/hip_runtime.h>

typedef unsigned short u16;
typedef __bf16 bf8 __attribute__((ext_vector_type(8)));
typedef __bf16 bf2 __attribute__((ext_vector_type(2)));
typedef float f4 __attribute__((ext_vector_type(4)));

typedef __attribute__((address_space(1))) const unsigned int gas_u32;
typedef __attribute__((address_space(3))) unsigned int las_u32;
#define ASYNC16(g, l) __builtin_amdgcn_global_load_lds((gas_u32*)(g), (las_u32*)(l), 16, 0, 0)

// pack two f32 -> bf16x2 word via HW cvt (compiler emits v_cvt_pk_bf16_f32, RNE).
// R1 lesson: hand-written cvt_pk asm had wrong half order; plain casts are the proven path.
__device__ __forceinline__ unsigned pkbf(float lo, float hi) {
    union { bf2 v; unsigned u; } t;
    t.v[0] = (__bf16)lo;
    t.v[1] = (__bf16)hi;
    return t.u;
}

__device__ __forceinline__ u16 bf1(float f) {
    union { __bf16 v; u16 u; } t;
    t.v = (__bf16)f;
    return t.u;
}

__device__ __forceinline__ float fexp2(float x) {
#if __has_builtin(__builtin_amdgcn_exp2f)
  return __builtin_amdgcn_exp2f(x);
#else
  return __expf(x * 0.69314718056f);
#endif
}

// ---------------- fp32 -> bf16 conversion of inputs + weights ----------------
__global__ __launch_bounds__(256) void cvt_all(
    const float* __restrict__ k_, const float* __restrict__ q_, const float* __restrict__ v_,
    const float* __restrict__ wq, const float* __restrict__ wk, const float* __restrict__ wv,
    const float* __restrict__ wo, u16* __restrict__ ws) {
  size_t e = ((size_t)blockIdx.x * 256 + threadIdx.x) * 8;
  const float* src;
  if      (e <  4194304) src = k_ + e;
  else if (e <  8388608) src = q_ + (e - 4194304);
  else if (e < 12582912) src = v_ + (e - 8388608);
  else if (e < 13631488) src = wq + (e - 12582912);
  else if (e < 14680064) src = wk + (e - 13631488);
  else if (e < 15728640) src = wv + (e - 14680064);
  else                   src = wo + (e - 15728640);
  float4 f0 = ((const float4*)src)[0];
  float4 f1 = ((const float4*)src)[1];
  uint4 o;
  o.x = pkbf(f0.x, f0.y);
  o.y = pkbf(f0.z, f0.w);
  o.z = pkbf(f1.x, f1.y);
  o.w = pkbf(f1.z, f1.w);
  *(uint4*)(ws + e) = o;
}

// ---------------- GEMM tile v2: BK=64 (half the barriers), chunk-XOR swizzled LDS ----------------
// C = scale * (A[M,K] @ B[N,K]^T), K=1024. BM x 128 tile, 256 threads = 2x2 waves.
// LDS row stride 64 elem (128 B); 16B chunk c stored at c^(row&7) (swizzle applied on the
// GLOBAL address per global_load_lds's linear-LDS requirement). b128 frag reads are 2-way.
template<int BM, bool FINAL>
__device__ __forceinline__ void gemm_tile(const u16* __restrict__ A, const u16* __restrict__ Bm,
                                          u16* __restrict__ Cb, float* __restrict__ Cf,
                                          const float* __restrict__ bias, float scale,
                                          int bm, int bn, int ldc) {
  __shared__ u16 As[BM*64];
  __shared__ u16 Bs[128*64];
  const int tid = threadIdx.x;
  const int wave = tid >> 6, lane = tid & 63;
  const int wm = wave >> 1, wn = wave & 1;
  const int quad = lane >> 4, l16 = lane & 15;
  const int MI = BM / 32;

  f4 acc[MI][4];
  const f4 zz = {0.f, 0.f, 0.f, 0.f};
  #pragma unroll
  for (int i = 0; i < MI; i++)
    #pragma unroll
    for (int j = 0; j < 4; j++) acc[i][j] = zz;

  // staging: thread t covers row kr=t>>3 (+p*32), swizzled chunk cs
  const int kr = tid >> 3;
  const int cs = (tid & 7) ^ (kr & 7);
  const u16* ga = A  + (size_t)(bm*BM  + kr)*1024 + cs*8;
  const u16* gb = Bm + (size_t)(bn*128 + kr)*1024 + cs*8;
  u16* la = As + tid*8;
  u16* lb = Bs + tid*8;

  for (int kt = 0; kt < 1024; kt += 64) {
    #pragma unroll
    for (int p = 0; p < BM/32; p++) ASYNC16(ga + (size_t)(p*32)*1024 + kt, la + p*2048);
    #pragma unroll
    for (int p = 0; p < 4; p++)     ASYNC16(gb + (size_t)(p*32)*1024 + kt, lb + p*2048);
    __syncthreads();               // drains DMA -> tile visible
    #pragma unroll
    for (int kk = 0; kk < 2; kk++) {
      bf8 af[MI];
      #pragma unroll
      for (int mi = 0; mi < MI; mi++)
        af[mi] = *(const bf8*)(As + (wm*(BM/2) + mi*16 + l16)*64 + (((kk*4 + quad) ^ (l16 & 7))*8));
      #pragma unroll
      for (int ni = 0; ni < 4; ni++) {
        bf8 bfr = *(const bf8*)(Bs + (wn*64 + ni*16 + l16)*64 + (((kk*4 + quad) ^ (l16 & 7))*8));
        #pragma unroll
        for (int mi = 0; mi < MI; mi++)
          acc[mi][ni] = __builtin_amdgcn_mfma_f32_16x16x32_bf16(af[mi], bfr, acc[mi][ni], 0, 0, 0);
      }
    }
    __syncthreads();               // all frag reads done before next DMA overwrites
  }

  #pragma unroll
  for (int mi = 0; mi < MI; mi++)
    #pragma unroll
    for (int ni = 0; ni < 4; ni++) {
      const int col = bn*128 + wn*64 + ni*16 + l16;
      #pragma unroll
      for (int r = 0; r < 4; r++) {
        const int row = bm*BM + wm*(BM/2) + mi*16 + quad*4 + r;
        if (FINAL) Cf[(size_t)row*ldc + col] = acc[mi][ni][r] + bias[col];
        else       Cb[(size_t)row*ldc + col] = bf1(acc[mi][ni][r] * scale);
      }
    }
}

// Q pre-scaled by 0.125*log2(e) so flash_attn uses raw exp2.
#define QSCALE 0.180336880f

// Grid (32,8,3): x = M-tile -> XCD = bm%8, so A-panels are XCD-resident and W streams
// through each XCD's L2 (2 MB < 4 MB). z=2 computes V^T = Wv@xv^T (coalesced transposed out).
__global__ __launch_bounds__(256, 3) void gemm_qkv(
    const u16* __restrict__ xq, const u16* __restrict__ xk, const u16* __restrict__ xv,
    const u16* __restrict__ wq, const u16* __restrict__ wk, const u16* __restrict__ wv,
    u16* __restrict__ Qo, u16* __restrict__ Ko, u16* __restrict__ Vto) {
  if (blockIdx.z == 0)
    gemm_tile<128,false>(xq, wq, Qo, nullptr, nullptr, QSCALE, blockIdx.x, blockIdx.y, 1024);
  else if (blockIdx.z == 1)
    gemm_tile<128,false>(xk, wk, Ko, nullptr, nullptr, 1.0f, blockIdx.x, blockIdx.y, 1024);
  else
    gemm_tile<128,false>(wv, xv, Vto, nullptr, nullptr, 1.0f, blockIdx.y, blockIdx.x, 4096);
}

// Grid (64,8): x = M-tile (64 rows) -> XCD-aligned ctx panels.
__global__ __launch_bounds__(256, 2) void gemm_out(
    const u16* __restrict__ ctx, const u16* __restrict__ wo,
    const float* __restrict__ bias, float* __restrict__ out) {
  gemm_tile<64,true>(ctx, wo, nullptr, out, bias, 1.0f, blockIdx.x, blockIdx.y, 1024);
}

// ---------------- flash attention v7 (proven 45.3 us): permuted-key QK^T + setprio ----------
// Grid (16,32,2): x = h -> XCD = h%8: each XCD caches 4 K/V slabs (2 MB) across its 32 qt blocks.
// v6: permuted-key QK^T makes P lane-local (frag f reads K row (l16>>2)*8+f*4+(l16&3)), so
// exp2+cvt_pk feed PV's B-operand directly — zero LDS traffic for P.
// v7: 4 independent blocks/CU at different phases -> T5: setprio(1) around MFMA clusters.
// R6/R7 lesson: dbuf (2 blk/CU) and phase-split staging (3 barriers) both LOSE vs this —
// at 4 blocks/CU the inter-block TLP already hides the staging drain.
__global__ __launch_bounds__(256, 4) void flash_attn(
    const u16* __restrict__ Qg, const u16* __restrict__ Kg,
    const u16* __restrict__ Vtg, u16* __restrict__ ctx) {
  __shared__ uint4 smem4[2208];              // 35328 B
  u16* Ks = (u16*)smem4;                     // [0,16384) K [128 key][64 d], 16B-chunk c^=(key&7)
  u16* Vt = (u16*)smem4 + 8192;              // [16384,32768) V^T [64 d][128 key], c^=(d&15)
  float* Of = (float*)smem4;                 // epilogue overlay: 2 x [64][68] f32 = 34816 B
  float* Lf = (float*)smem4 + 2*64*68;       // 128 f32 -> 35328 B total

  const int tid = threadIdx.x;
  const int wave = tid >> 6, lane = tid & 63;
  const int quad = lane >> 4, l16 = lane & 15;
  const int wq = wave >> 1, wk = wave & 1;
  const int h = blockIdx.x, qt = blockIdx.y, b = blockIdx.z;

  // Q B-frags (B[n=qrow=l16][k=dim=quad*8+j]); one-time global load
  bf8 qf[2][2];
  {
    const u16* qp = Qg + (size_t)(b*2048 + qt*64 + wq*32)*1024 + h*64;
    #pragma unroll
    for (int qs = 0; qs < 2; qs++)
      #pragma unroll
      for (int kc = 0; kc < 2; kc++)
        qf[qs][kc] = *(const bf8*)(qp + (size_t)(qs*16 + l16)*1024 + kc*32 + quad*8);
  }

  const f4 zz = {0.f, 0.f, 0.f, 0.f};
  f4 ot[4][2];                 // O^T acc: [d-sub][q-sub], elem (row=d=quad*4+r, col=qrow=l16)
  float lrow[2] = {0.f, 0.f};  // per-lane denominator partial
  #pragma unroll
  for (int ds = 0; ds < 4; ds++)
    #pragma unroll
    for (int qs = 0; qs < 2; qs++) ot[ds][qs] = zz;

  // staging bases (global side carries the XOR chunk-swizzle; LDS side linear)
  const int kr = tid >> 3;
  const u16* kga = Kg + (size_t)(b*2048 + kr)*1024 + h*64 + ((tid & 7) ^ (kr & 7))*8;
  const int vd = tid >> 4;
  const u16* vga = Vtg + (size_t)(h*64 + vd)*4096 + b*2048 + (((tid & 15) ^ vd))*8;
  u16* kld = Ks + tid*8;
  u16* vld = Vt + tid*8;

  // permuted K-row bases for the two QK frags (f=0,1): within a 32-key block,
  // frag f, lane (quad,l16) reads key-row (l16>>2)*8 + f*4 + (l16&3).
  const int prow0 = ((l16 >> 2) << 3) + (l16 & 3);      // f=0
  const int prow1 = prow0 + 4;                           // f=1

  for (int kv0 = 0; kv0 < 2048; kv0 += 128) {
    __syncthreads();               // previous tile fully consumed
    #pragma unroll
    for (int p = 0; p < 4; p++) ASYNC16(kga + (size_t)(kv0 + p*32)*1024, kld + p*2048);
    #pragma unroll
    for (int p = 0; p < 4; p++) ASYNC16(vga + (size_t)(p*16)*4096 + kv0, vld + p*2048);
    __syncthreads();               // drains vmcnt -> tile visible

    #pragma unroll
    for (int kb = 0; kb < 2; kb++) {
      // --- S^T = K @ Q^T, keys permuted so output is PV-operand-local ---
      f4 st[2][2];                 // [f][qs]: scores for keys quad*8 + f*4 + r
      #pragma unroll
      for (int f = 0; f < 2; f++)
        #pragma unroll
        for (int qs = 0; qs < 2; qs++) st[f][qs] = zz;
      __builtin_amdgcn_s_setprio(1);
      #pragma unroll
      for (int f = 0; f < 2; f++) {
        const int row = wk*64 + kb*32 + (f ? prow1 : prow0);
        #pragma unroll
        for (int kc = 0; kc < 2; kc++) {
          bf8 kf = *(const bf8*)(Ks + row*64 + (((kc*4 + quad) ^ (row & 7))*8));
          #pragma unroll
          for (int qs = 0; qs < 2; qs++)
            st[f][qs] = __builtin_amdgcn_mfma_f32_16x16x32_bf16(kf, qf[qs][kc], st[f][qs], 0, 0, 0);
        }
      }
      __builtin_amdgcn_s_setprio(0);
      // --- exp2, per-lane row-sum, cvt_pk straight into the PV B-frag ---
      bf8 pf[2];
      #pragma unroll
      for (int qs = 0; qs < 2; qs++) {
        float p0 = fexp2(st[0][qs][0]), p1 = fexp2(st[0][qs][1]);
        float p2 = fexp2(st[0][qs][2]), p3 = fexp2(st[0][qs][3]);
        float p4 = fexp2(st[1][qs][0]), p5 = fexp2(st[1][qs][1]);
        float p6 = fexp2(st[1][qs][2]), p7 = fexp2(st[1][qs][3]);
        lrow[qs] += ((p0 + p1) + (p2 + p3)) + ((p4 + p5) + (p6 + p7));
        union { uint4 u; bf8 v; } pu;
        pu.u.x = pkbf(p0, p1);     // keys quad*8 + 0,1
        pu.u.y = pkbf(p2, p3);     // keys quad*8 + 2,3
        pu.u.z = pkbf(p4, p5);     // keys quad*8 + 4,5
        pu.u.w = pkbf(p6, p7);     // keys quad*8 + 6,7
        pf[qs] = pu.v;
      }
      // --- O^T += V^T-frag @ P ---
      __builtin_amdgcn_s_setprio(1);
      #pragma unroll
      for (int ds = 0; ds < 4; ds++) {
        const int d = ds*16 + l16;
        bf8 vf = *(const bf8*)(Vt + d*128 + (((wk*8 + kb*4 + quad) ^ l16)*8));
        #pragma unroll
        for (int qs = 0; qs < 2; qs++)
          ot[ds][qs] = __builtin_amdgcn_mfma_f32_16x16x32_bf16(vf, pf[qs], ot[ds][qs], 0, 0, 0);
      }
      __builtin_amdgcn_s_setprio(0);
    }
  }

  // ---------------- epilogue: reduce key-stripes, transpose, normalize, store ----------------
  __syncthreads();                 // everyone done with Ks/Vt -> safe to overlay
  #pragma unroll
  for (int qs = 0; qs < 2; qs++) {
    lrow[qs] += __shfl_xor(lrow[qs], 16);
    lrow[qs] += __shfl_xor(lrow[qs], 32);
  }
  float* Ofw = Of + wk*(64*68);
  #pragma unroll
  for (int ds = 0; ds < 4; ds++)
    #pragma unroll
    for (int qs = 0; qs < 2; qs++)
      #pragma unroll
      for (int r = 0; r < 4; r++)
        Ofw[(wq*32 + qs*16 + l16)*68 + ds*16 + quad*4 + r] = ot[ds][qs][r];
  if (quad == 0) {
    Lf[wk*64 + wq*32 + l16]      = lrow[0];
    Lf[wk*64 + wq*32 + 16 + l16] = lrow[1];
  }
  __syncthreads();
  {
    const int qr = tid >> 2, dp = (tid & 3)*16;
    const float inv = 1.f / (Lf[qr] + Lf[64 + qr]);
    const float* o0 = Of + qr*68 + dp;
    const float* o1 = o0 + 64*68;
    unsigned ow[8];
    #pragma unroll
    for (int i = 0; i < 8; i++)
      ow[i] = pkbf((o0[2*i] + o1[2*i]) * inv, (o0[2*i+1] + o1[2*i+1]) * inv);
    u16* cp = ctx + (size_t)(b*2048 + qt*64 + qr)*1024 + h*64 + dp;
    *(uint4*)cp       = *(uint4*)&ow[0];
    *(uint4*)(cp + 8) = *(uint4*)&ow[4];
  }
}

extern "C" void kernel_launch(void* const* d_in, const int* in_sizes, int n_in,
                              void* d_out, int out_size, void* d_ws, size_t ws_size,
                              hipStream_t stream) {
  const float* key_  = (const float*)d_in[0];
  const float* query = (const float*)d_in[1];
  const float* value = (const float*)d_in[2];
  const float* Wq = (const float*)d_in[3];
  const float* Wk = (const float*)d_in[4];
  const float* Wv = (const float*)d_in[5];
  const float* Wo = (const float*)d_in[6];
  const float* bo = (const float*)d_in[7];
  float* out = (float*)d_out;

  u16* ws  = (u16*)d_ws;                 // needs 67.1 MB of workspace
  u16* xkb = ws;
  u16* xqb = ws + 4194304;
  u16* xvb = ws + 8388608;
  u16* Wqb = ws + 12582912;
  u16* Wkb = ws + 13631488;
  u16* Wvb = ws + 14680064;
  u16* Wob = ws + 15728640;
  u16* Qb  = ws + 16777216;              // Q (pre-scaled by 0.125*log2e) [4096,1024] bf16
  u16* Kb  = ws + 20971520;              // K [4096,1024] bf16
  u16* Vtb = ws + 25165824;              // V^T [1024,4096] bf16
  u16* Cb  = ws + 29360128;              // attention context [4096,1024] bf16

  cvt_all<<<8192, 256, 0, stream>>>(key_, query, value, Wq, Wk, Wv, Wo, ws);
  gemm_qkv<<<dim3(32, 8, 3), 256, 0, stream>>>(xqb, xkb, xvb, Wqb, Wkb, Wvb, Qb, Kb, Vtb);
  flash_attn<<<dim3(16, 32, 2), 256, 0, stream>>>(Qb, Kb, Vtb, Cb);
  gemm_out<<<dim3(64, 8), 256, 0, stream>>>(Cb, Wob, bo, out);
}

// Round 9
// 200.920 us; speedup vs baseline: 1.0108x; 1.0108x over previous
//
#include <hip/hip_runtime.h>

typedef unsigned short u16;
typedef __bf16 bf8 __attribute__((ext_vector_type(8)));
typedef __bf16 bf2 __attribute__((ext_vector_type(2)));
typedef float f4 __attribute__((ext_vector_type(4)));

typedef __attribute__((address_space(1))) const unsigned int gas_u32;
typedef __attribute__((address_space(3))) unsigned int las_u32;
#define ASYNC16(g, l) __builtin_amdgcn_global_load_lds((gas_u32*)(g), (las_u32*)(l), 16, 0, 0)

// pack two f32 -> bf16x2 word via HW cvt (compiler emits v_cvt_pk_bf16_f32, RNE).
// R1 lesson: hand-written cvt_pk asm had wrong half order; plain casts are the proven path.
__device__ __forceinline__ unsigned pkbf(float lo, float hi) {
    union { bf2 v; unsigned u; } t;
    t.v[0] = (__bf16)lo;
    t.v[1] = (__bf16)hi;
    return t.u;
}

__device__ __forceinline__ u16 bf1(float f) {
    union { __bf16 v; u16 u; } t;
    t.v = (__bf16)f;
    return t.u;
}

__device__ __forceinline__ float fexp2(float x) {
#if __has_builtin(__builtin_amdgcn_exp2f)
  return __builtin_amdgcn_exp2f(x);
#else
  return __expf(x * 0.69314718056f);
#endif
}

// ---------------- fp32 -> bf16 conversion of inputs + weights ----------------
__global__ __launch_bounds__(256) void cvt_all(
    const float* __restrict__ k_, const float* __restrict__ q_, const float* __restrict__ v_,
    const float* __restrict__ wq, const float* __restrict__ wk, const float* __restrict__ wv,
    const float* __restrict__ wo, u16* __restrict__ ws) {
  size_t e = ((size_t)blockIdx.x * 256 + threadIdx.x) * 8;
  const float* src;
  if      (e <  4194304) src = k_ + e;
  else if (e <  8388608) src = q_ + (e - 4194304);
  else if (e < 12582912) src = v_ + (e - 8388608);
  else if (e < 13631488) src = wq + (e - 12582912);
  else if (e < 14680064) src = wk + (e - 13631488);
  else if (e < 15728640) src = wv + (e - 14680064);
  else                   src = wo + (e - 15728640);
  float4 f0 = ((const float4*)src)[0];
  float4 f1 = ((const float4*)src)[1];
  uint4 o;
  o.x = pkbf(f0.x, f0.y);
  o.y = pkbf(f0.z, f0.w);
  o.z = pkbf(f1.x, f1.y);
  o.w = pkbf(f1.z, f1.w);
  *(uint4*)(ws + e) = o;
}

// ---------------- GEMM tile v2: BK=64 (half the barriers), chunk-XOR swizzled LDS ----------------
// C = scale * (A[M,K] @ B[N,K]^T), K=1024. BM x 128 tile, 256 threads = 2x2 waves.
// LDS row stride 64 elem (128 B); 16B chunk c stored at c^(row&7) (swizzle applied on the
// GLOBAL address per global_load_lds's linear-LDS requirement). b128 frag reads are 2-way.
template<int BM, bool FINAL>
__device__ __forceinline__ void gemm_tile(const u16* __restrict__ A, const u16* __restrict__ Bm,
                                          u16* __restrict__ Cb, float* __restrict__ Cf,
                                          const float* __restrict__ bias, float scale,
                                          int bm, int bn, int ldc) {
  __shared__ u16 As[BM*64];
  __shared__ u16 Bs[128*64];
  const int tid = threadIdx.x;
  const int wave = tid >> 6, lane = tid & 63;
  const int wm = wave >> 1, wn = wave & 1;
  const int quad = lane >> 4, l16 = lane & 15;
  const int MI = BM / 32;

  f4 acc[MI][4];
  const f4 zz = {0.f, 0.f, 0.f, 0.f};
  #pragma unroll
  for (int i = 0; i < MI; i++)
    #pragma unroll
    for (int j = 0; j < 4; j++) acc[i][j] = zz;

  // staging: thread t covers row kr=t>>3 (+p*32), swizzled chunk cs
  const int kr = tid >> 3;
  const int cs = (tid & 7) ^ (kr & 7);
  const u16* ga = A  + (size_t)(bm*BM  + kr)*1024 + cs*8;
  const u16* gb = Bm + (size_t)(bn*128 + kr)*1024 + cs*8;
  u16* la = As + tid*8;
  u16* lb = Bs + tid*8;

  for (int kt = 0; kt < 1024; kt += 64) {
    #pragma unroll
    for (int p = 0; p < BM/32; p++) ASYNC16(ga + (size_t)(p*32)*1024 + kt, la + p*2048);
    #pragma unroll
    for (int p = 0; p < 4; p++)     ASYNC16(gb + (size_t)(p*32)*1024 + kt, lb + p*2048);
    __syncthreads();               // drains DMA -> tile visible
    #pragma unroll
    for (int kk = 0; kk < 2; kk++) {
      bf8 af[MI];
      #pragma unroll
      for (int mi = 0; mi < MI; mi++)
        af[mi] = *(const bf8*)(As + (wm*(BM/2) + mi*16 + l16)*64 + (((kk*4 + quad) ^ (l16 & 7))*8));
      #pragma unroll
      for (int ni = 0; ni < 4; ni++) {
        bf8 bfr = *(const bf8*)(Bs + (wn*64 + ni*16 + l16)*64 + (((kk*4 + quad) ^ (l16 & 7))*8));
        #pragma unroll
        for (int mi = 0; mi < MI; mi++)
          acc[mi][ni] = __builtin_amdgcn_mfma_f32_16x16x32_bf16(af[mi], bfr, acc[mi][ni], 0, 0, 0);
      }
    }
    __syncthreads();               // all frag reads done before next DMA overwrites
  }

  #pragma unroll
  for (int mi = 0; mi < MI; mi++)
    #pragma unroll
    for (int ni = 0; ni < 4; ni++) {
      const int col = bn*128 + wn*64 + ni*16 + l16;
      #pragma unroll
      for (int r = 0; r < 4; r++) {
        const int row = bm*BM + wm*(BM/2) + mi*16 + quad*4 + r;
        if (FINAL) Cf[(size_t)row*ldc + col] = acc[mi][ni][r] + bias[col];
        else       Cb[(size_t)row*ldc + col] = bf1(acc[mi][ni][r] * scale);
      }
    }
}

// Q pre-scaled by 0.125*log2(e) so flash_attn uses raw exp2.
#define QSCALE 0.180336880f

// Grid (32,8,3): x = M-tile -> XCD = bm%8, so A-panels are XCD-resident and W streams
// through each XCD's L2 (2 MB < 4 MB). z=2 computes V^T = Wv@xv^T (coalesced transposed out).
__global__ __launch_bounds__(256, 3) void gemm_qkv(
    const u16* __restrict__ xq, const u16* __restrict__ xk, const u16* __restrict__ xv,
    const u16* __restrict__ wq, const u16* __restrict__ wk, const u16* __restrict__ wv,
    u16* __restrict__ Qo, u16* __restrict__ Ko, u16* __restrict__ Vto) {
  if (blockIdx.z == 0)
    gemm_tile<128,false>(xq, wq, Qo, nullptr, nullptr, QSCALE, blockIdx.x, blockIdx.y, 1024);
  else if (blockIdx.z == 1)
    gemm_tile<128,false>(xk, wk, Ko, nullptr, nullptr, 1.0f, blockIdx.x, blockIdx.y, 1024);
  else
    gemm_tile<128,false>(wv, xv, Vto, nullptr, nullptr, 1.0f, blockIdx.y, blockIdx.x, 4096);
}

// Grid (64,8): x = M-tile (64 rows) -> XCD-aligned ctx panels.
__global__ __launch_bounds__(256, 2) void gemm_out(
    const u16* __restrict__ ctx, const u16* __restrict__ wo,
    const float* __restrict__ bias, float* __restrict__ out) {
  gemm_tile<64,true>(ctx, wo, nullptr, out, bias, 1.0f, blockIdx.x, blockIdx.y, 1024);
}

// ---------------- flash attention v10: v7 + conflict-free K swizzle for permuted reads -----
// Grid (16,32,2): x = h -> XCD = h%8: each XCD caches 4 K/V slabs (2 MB) across its 32 qt blocks.
// v6: permuted-key QK^T makes P lane-local (frag f reads K row (l16>>2)*8+f*4+(l16&3)), so
// exp2+cvt_pk feed PV's B-operand directly — zero LDS traffic for P. v7: setprio on MFMA.
// v10: the v6 permutation broke the old c^(row&7) swizzle — permuted rows have row&7 in
// {b+4f} = 4 values only -> 4 bank groups -> 4-way conflict on every K frag read (matches the
// measured 2.1M conflict cycles). New swizzle KSW(r) = ((r>>3)&1)<<2 | (r&3): over the read
// set it equals ((l16>>2)&1)<<2|(l16&3), 8 distinct values across 16 lanes -> all 8 bank
// groups -> conflict-free. KSW is invariant under +32p (bits 0-1,3 only) so one cs per thread
// serves all 4 staging loads. R6/R7 lesson: keep single buffer + 4 blocks/CU (TLP hides DMA).
#define KSW(r) (((((r) >> 3) & 1) << 2) | ((r) & 3))
__global__ __launch_bounds__(256, 4) void flash_attn(
    const u16* __restrict__ Qg, const u16* __restrict__ Kg,
    const u16* __restrict__ Vtg, u16* __restrict__ ctx) {
  __shared__ uint4 smem4[2208];              // 35328 B
  u16* Ks = (u16*)smem4;                     // [0,16384) K [128 key][64 d], 16B-chunk c^=KSW(key)
  u16* Vt = (u16*)smem4 + 8192;              // [16384,32768) V^T [64 d][128 key], c^=(d&15)
  float* Of = (float*)smem4;                 // epilogue overlay: 2 x [64][68] f32 = 34816 B
  float* Lf = (float*)smem4 + 2*64*68;       // 128 f32 -> 35328 B total

  const int tid = threadIdx.x;
  const int wave = tid >> 6, lane = tid & 63;
  const int quad = lane >> 4, l16 = lane & 15;
  const int wq = wave >> 1, wk = wave & 1;
  const int h = blockIdx.x, qt = blockIdx.y, b = blockIdx.z;

  // Q B-frags (B[n=qrow=l16][k=dim=quad*8+j]); one-time global load
  bf8 qf[2][2];
  {
    const u16* qp = Qg + (size_t)(b*2048 + qt*64 + wq*32)*1024 + h*64;
    #pragma unroll
    for (int qs = 0; qs < 2; qs++)
      #pragma unroll
      for (int kc = 0; kc < 2; kc++)
        qf[qs][kc] = *(const bf8*)(qp + (size_t)(qs*16 + l16)*1024 + kc*32 + quad*8);
  }

  const f4 zz = {0.f, 0.f, 0.f, 0.f};
  f4 ot[4][2];                 // O^T acc: [d-sub][q-sub], elem (row=d=quad*4+r, col=qrow=l16)
  float lrow[2] = {0.f, 0.f};  // per-lane denominator partial
  #pragma unroll
  for (int ds = 0; ds < 4; ds++)
    #pragma unroll
    for (int qs = 0; qs < 2; qs++) ot[ds][qs] = zz;

  // staging bases (global side carries the XOR chunk-swizzle; LDS side linear)
  const int kr = tid >> 3;
  const u16* kga = Kg + (size_t)(b*2048 + kr)*1024 + h*64 + ((tid & 7) ^ KSW(kr))*8;
  const int vd = tid >> 4;
  const u16* vga = Vtg + (size_t)(h*64 + vd)*4096 + b*2048 + (((tid & 15) ^ vd))*8;
  u16* kld = Ks + tid*8;
  u16* vld = Vt + tid*8;

  // permuted K-row bases for the two QK frags (f=0,1): within a 32-key block,
  // frag f, lane (quad,l16) reads key-row (l16>>2)*8 + f*4 + (l16&3).
  const int prow0 = ((l16 >> 2) << 3) + (l16 & 3);      // f=0
  const int prow1 = prow0 + 4;                           // f=1
  const int ksw   = (((l16 >> 2) & 1) << 2) | (l16 & 3); // = KSW(row) for this lane's rows

  for (int kv0 = 0; kv0 < 2048; kv0 += 128) {
    __syncthreads();               // previous tile fully consumed
    #pragma unroll
    for (int p = 0; p < 4; p++) ASYNC16(kga + (size_t)(kv0 + p*32)*1024, kld + p*2048);
    #pragma unroll
    for (int p = 0; p < 4; p++) ASYNC16(vga + (size_t)(p*16)*4096 + kv0, vld + p*2048);
    __syncthreads();               // drains vmcnt -> tile visible

    #pragma unroll
    for (int kb = 0; kb < 2; kb++) {
      // --- S^T = K @ Q^T, keys permuted so output is PV-operand-local ---
      f4 st[2][2];                 // [f][qs]: scores for keys quad*8 + f*4 + r
      #pragma unroll
      for (int f = 0; f < 2; f++)
        #pragma unroll
        for (int qs = 0; qs < 2; qs++) st[f][qs] = zz;
      __builtin_amdgcn_s_setprio(1);
      #pragma unroll
      for (int f = 0; f < 2; f++) {
        const int row = wk*64 + kb*32 + (f ? prow1 : prow0);
        #pragma unroll
        for (int kc = 0; kc < 2; kc++) {
          bf8 kf = *(const bf8*)(Ks + row*64 + (((kc*4 + quad) ^ ksw)*8));
          #pragma unroll
          for (int qs = 0; qs < 2; qs++)
            st[f][qs] = __builtin_amdgcn_mfma_f32_16x16x32_bf16(kf, qf[qs][kc], st[f][qs], 0, 0, 0);
        }
      }
      __builtin_amdgcn_s_setprio(0);
      // --- exp2, per-lane row-sum, cvt_pk straight into the PV B-frag ---
      bf8 pf[2];
      #pragma unroll
      for (int qs = 0; qs < 2; qs++) {
        float p0 = fexp2(st[0][qs][0]), p1 = fexp2(st[0][qs][1]);
        float p2 = fexp2(st[0][qs][2]), p3 = fexp2(st[0][qs][3]);
        float p4 = fexp2(st[1][qs][0]), p5 = fexp2(st[1][qs][1]);
        float p6 = fexp2(st[1][qs][2]), p7 = fexp2(st[1][qs][3]);
        lrow[qs] += ((p0 + p1) + (p2 + p3)) + ((p4 + p5) + (p6 + p7));
        union { uint4 u; bf8 v; } pu;
        pu.u.x = pkbf(p0, p1);     // keys quad*8 + 0,1
        pu.u.y = pkbf(p2, p3);     // keys quad*8 + 2,3
        pu.u.z = pkbf(p4, p5);     // keys quad*8 + 4,5
        pu.u.w = pkbf(p6, p7);     // keys quad*8 + 6,7
        pf[qs] = pu.v;
      }
      // --- O^T += V^T-frag @ P ---
      __builtin_amdgcn_s_setprio(1);
      #pragma unroll
      for (int ds = 0; ds < 4; ds++) {
        const int d = ds*16 + l16;
        bf8 vf = *(const bf8*)(Vt + d*128 + (((wk*8 + kb*4 + quad) ^ l16)*8));
        #pragma unroll
        for (int qs = 0; qs < 2; qs++)
          ot[ds][qs] = __builtin_amdgcn_mfma_f32_16x16x32_bf16(vf, pf[qs], ot[ds][qs], 0, 0, 0);
      }
      __builtin_amdgcn_s_setprio(0);
    }
  }

  // ---------------- epilogue: reduce key-stripes, transpose, normalize, store ----------------
  __syncthreads();                 // everyone done with Ks/Vt -> safe to overlay
  #pragma unroll
  for (int qs = 0; qs < 2; qs++) {
    lrow[qs] += __shfl_xor(lrow[qs], 16);
    lrow[qs] += __shfl_xor(lrow[qs], 32);
  }
  float* Ofw = Of + wk*(64*68);
  #pragma unroll
  for (int ds = 0; ds < 4; ds++)
    #pragma unroll
    for (int qs = 0; qs < 2; qs++)
      #pragma unroll
      for (int r = 0; r < 4; r++)
        Ofw[(wq*32 + qs*16 + l16)*68 + ds*16 + quad*4 + r] = ot[ds][qs][r];
  if (quad == 0) {
    Lf[wk*64 + wq*32 + l16]      = lrow[0];
    Lf[wk*64 + wq*32 + 16 + l16] = lrow[1];
  }
  __syncthreads();
  {
    const int qr = tid >> 2, dp = (tid & 3)*16;
    const float inv = 1.f / (Lf[qr] + Lf[64 + qr]);
    const float* o0 = Of + qr*68 + dp;
    const float* o1 = o0 + 64*68;
    unsigned ow[8];
    #pragma unroll
    for (int i = 0; i < 8; i++)
      ow[i] = pkbf((o0[2*i] + o1[2*i]) * inv, (o0[2*i+1] + o1[2*i+1]) * inv);
    u16* cp = ctx + (size_t)(b*2048 + qt*64 + qr)*1024 + h*64 + dp;
    *(uint4*)cp       = *(uint4*)&ow[0];
    *(uint4*)(cp + 8) = *(uint4*)&ow[4];
  }
}

extern "C" void kernel_launch(void* const* d_in, const int* in_sizes, int n_in,
                              void* d_out, int out_size, void* d_ws, size_t ws_size,
                              hipStream_t stream) {
  const float* key_  = (const float*)d_in[0];
  const float* query = (const float*)d_in[1];
  const float* value = (const float*)d_in[2];
  const float* Wq = (const float*)d_in[3];
  const float* Wk = (const float*)d_in[4];
  const float* Wv = (const float*)d_in[5];
  const float* Wo = (const float*)d_in[6];
  const float* bo = (const float*)d_in[7];
  float* out = (float*)d_out;

  u16* ws  = (u16*)d_ws;                 // needs 67.1 MB of workspace
  u16* xkb = ws;
  u16* xqb = ws + 4194304;
  u16* xvb = ws + 8388608;
  u16* Wqb = ws + 12582912;
  u16* Wkb = ws + 13631488;
  u16* Wvb = ws + 14680064;
  u16* Wob = ws + 15728640;
  u16* Qb  = ws + 16777216;              // Q (pre-scaled by 0.125*log2e) [4096,1024] bf16
  u16* Kb  = ws + 20971520;              // K [4096,1024] bf16
  u16* Vtb = ws + 25165824;              // V^T [1024,4096] bf16
  u16* Cb  = ws + 29360128;              // attention context [4096,1024] bf16

  cvt_all<<<8192, 256, 0, stream>>>(key_, query, value, Wq, Wk, Wv, Wo, ws);
  gemm_qkv<<<dim3(32, 8, 3), 256, 0, stream>>>(xqb, xkb, xvb, Wqb, Wkb, Wvb, Qb, Kb, Vtb);
  flash_attn<<<dim3(16, 32, 2), 256, 0, stream>>>(Qb, Kb, Vtb, Cb);
  gemm_out<<<dim3(64, 8), 256, 0, stream>>>(Cb, Wob, bo, out);
}

// Round 10
// 199.043 us; speedup vs baseline: 1.0203x; 1.0094x over previous
//
#include <hip/hip_runtime.h>

typedef unsigned short u16;
typedef __bf16 bf8 __attribute__((ext_vector_type(8)));
typedef __bf16 bf2 __attribute__((ext_vector_type(2)));
typedef float f4 __attribute__((ext_vector_type(4)));

typedef __attribute__((address_space(1))) const unsigned int gas_u32;
typedef __attribute__((address_space(3))) unsigned int las_u32;
#define ASYNC16(g, l) __builtin_amdgcn_global_load_lds((gas_u32*)(g), (las_u32*)(l), 16, 0, 0)

// pack two f32 -> bf16x2 word via HW cvt (compiler emits v_cvt_pk_bf16_f32, RNE).
// R1 lesson: hand-written cvt_pk asm had wrong half order; plain casts are the proven path.
__device__ __forceinline__ unsigned pkbf(float lo, float hi) {
    union { bf2 v; unsigned u; } t;
    t.v[0] = (__bf16)lo;
    t.v[1] = (__bf16)hi;
    return t.u;
}

__device__ __forceinline__ u16 bf1(float f) {
    union { __bf16 v; u16 u; } t;
    t.v = (__bf16)f;
    return t.u;
}

__device__ __forceinline__ float fexp2(float x) {
#if __has_builtin(__builtin_amdgcn_exp2f)
  return __builtin_amdgcn_exp2f(x);
#else
  return __expf(x * 0.69314718056f);
#endif
}

// ---------------- fp32 -> bf16 conversion of inputs + weights ----------------
__global__ __launch_bounds__(256) void cvt_all(
    const float* __restrict__ k_, const float* __restrict__ q_, const float* __restrict__ v_,
    const float* __restrict__ wq, const float* __restrict__ wk, const float* __restrict__ wv,
    const float* __restrict__ wo, u16* __restrict__ ws) {
  size_t e = ((size_t)blockIdx.x * 256 + threadIdx.x) * 8;
  const float* src;
  if      (e <  4194304) src = k_ + e;
  else if (e <  8388608) src = q_ + (e - 4194304);
  else if (e < 12582912) src = v_ + (e - 8388608);
  else if (e < 13631488) src = wq + (e - 12582912);
  else if (e < 14680064) src = wk + (e - 13631488);
  else if (e < 15728640) src = wv + (e - 14680064);
  else                   src = wo + (e - 15728640);
  float4 f0 = ((const float4*)src)[0];
  float4 f1 = ((const float4*)src)[1];
  uint4 o;
  o.x = pkbf(f0.x, f0.y);
  o.y = pkbf(f0.z, f0.w);
  o.z = pkbf(f1.x, f1.y);
  o.w = pkbf(f1.z, f1.w);
  *(uint4*)(ws + e) = o;
}

// ---------------- GEMM tile v2: BK=64 (half the barriers), chunk-XOR swizzled LDS ----------------
// C = scale * (A[M,K] @ B[N,K]^T), K=1024. BM x 128 tile, 256 threads = 2x2 waves.
// LDS row stride 64 elem (128 B); 16B chunk c stored at c^(row&7) (swizzle applied on the
// GLOBAL address per global_load_lds's linear-LDS requirement). b128 frag reads are 2-way.
template<int BM, bool FINAL>
__device__ __forceinline__ void gemm_tile(const u16* __restrict__ A, const u16* __restrict__ Bm,
                                          u16* __restrict__ Cb, float* __restrict__ Cf,
                                          const float* __restrict__ bias, float scale,
                                          int bm, int bn, int ldc) {
  __shared__ u16 As[BM*64];
  __shared__ u16 Bs[128*64];
  const int tid = threadIdx.x;
  const int wave = tid >> 6, lane = tid & 63;
  const int wm = wave >> 1, wn = wave & 1;
  const int quad = lane >> 4, l16 = lane & 15;
  const int MI = BM / 32;

  f4 acc[MI][4];
  const f4 zz = {0.f, 0.f, 0.f, 0.f};
  #pragma unroll
  for (int i = 0; i < MI; i++)
    #pragma unroll
    for (int j = 0; j < 4; j++) acc[i][j] = zz;

  // staging: thread t covers row kr=t>>3 (+p*32), swizzled chunk cs
  const int kr = tid >> 3;
  const int cs = (tid & 7) ^ (kr & 7);
  const u16* ga = A  + (size_t)(bm*BM  + kr)*1024 + cs*8;
  const u16* gb = Bm + (size_t)(bn*128 + kr)*1024 + cs*8;
  u16* la = As + tid*8;
  u16* lb = Bs + tid*8;

  for (int kt = 0; kt < 1024; kt += 64) {
    #pragma unroll
    for (int p = 0; p < BM/32; p++) ASYNC16(ga + (size_t)(p*32)*1024 + kt, la + p*2048);
    #pragma unroll
    for (int p = 0; p < 4; p++)     ASYNC16(gb + (size_t)(p*32)*1024 + kt, lb + p*2048);
    __syncthreads();               // drains DMA -> tile visible
    #pragma unroll
    for (int kk = 0; kk < 2; kk++) {
      bf8 af[MI];
      #pragma unroll
      for (int mi = 0; mi < MI; mi++)
        af[mi] = *(const bf8*)(As + (wm*(BM/2) + mi*16 + l16)*64 + (((kk*4 + quad) ^ (l16 & 7))*8));
      #pragma unroll
      for (int ni = 0; ni < 4; ni++) {
        bf8 bfr = *(const bf8*)(Bs + (wn*64 + ni*16 + l16)*64 + (((kk*4 + quad) ^ (l16 & 7))*8));
        #pragma unroll
        for (int mi = 0; mi < MI; mi++)
          acc[mi][ni] = __builtin_amdgcn_mfma_f32_16x16x32_bf16(af[mi], bfr, acc[mi][ni], 0, 0, 0);
      }
    }
    __syncthreads();               // all frag reads done before next DMA overwrites
  }

  #pragma unroll
  for (int mi = 0; mi < MI; mi++)
    #pragma unroll
    for (int ni = 0; ni < 4; ni++) {
      const int col = bn*128 + wn*64 + ni*16 + l16;
      #pragma unroll
      for (int r = 0; r < 4; r++) {
        const int row = bm*BM + wm*(BM/2) + mi*16 + quad*4 + r;
        if (FINAL) Cf[(size_t)row*ldc + col] = acc[mi][ni][r] + bias[col];
        else       Cb[(size_t)row*ldc + col] = bf1(acc[mi][ni][r] * scale);
      }
    }
}

// Q pre-scaled by 0.125*log2(e) so flash_attn uses raw exp2.
#define QSCALE 0.180336880f

// Grid (32,8,3): x = M-tile -> XCD = bm%8, so A-panels are XCD-resident and W streams
// through each XCD's L2 (2 MB < 4 MB). z=2 computes V^T = Wv@xv^T (coalesced transposed out).
__global__ __launch_bounds__(256, 3) void gemm_qkv(
    const u16* __restrict__ xq, const u16* __restrict__ xk, const u16* __restrict__ xv,
    const u16* __restrict__ wq, const u16* __restrict__ wk, const u16* __restrict__ wv,
    u16* __restrict__ Qo, u16* __restrict__ Ko, u16* __restrict__ Vto) {
  if (blockIdx.z == 0)
    gemm_tile<128,false>(xq, wq, Qo, nullptr, nullptr, QSCALE, blockIdx.x, blockIdx.y, 1024);
  else if (blockIdx.z == 1)
    gemm_tile<128,false>(xk, wk, Ko, nullptr, nullptr, 1.0f, blockIdx.x, blockIdx.y, 1024);
  else
    gemm_tile<128,false>(wv, xv, Vto, nullptr, nullptr, 1.0f, blockIdx.y, blockIdx.x, 4096);
}

// Grid (64,8): x = M-tile (64 rows) -> XCD-aligned ctx panels.
__global__ __launch_bounds__(256, 2) void gemm_out(
    const u16* __restrict__ ctx, const u16* __restrict__ wo,
    const float* __restrict__ bias, float* __restrict__ out) {
  gemm_tile<64,true>(ctx, wo, nullptr, out, bias, 1.0f, blockIdx.x, blockIdx.y, 1024);
}

// ---------------- flash attention v11: 64-key tiles, double-buffered in 32KB, counted vmcnt --
// Grid (16,32,2): x = h -> XCD = h%8: each XCD caches 4 K/V slabs (2 MB) across its 32 qt blocks.
// v6: permuted-key QK^T makes P lane-local -> P feeds PV's B-operand directly (zero LDS for P).
// v7: setprio(1) around MFMA clusters. v10: KSW swizzle -> bank conflicts = 0 (verified R9).
// v11: R6's dbuf schedule failed only via occupancy (64KB -> 2 blk/CU). Halving the KV tile to
// 64 keys gives 2 x 16KB buffers = 32KB -> occupancy 4 PRESERVED, and the tile-top vmcnt(0)
// drain becomes a counted vmcnt(4): tile t's 4 loads were issued a full compute-phase earlier.
// Per tile: wk covers 32 of 64 keys (kb loop gone). 2 barriers/tile, 32 tiles.
#define KSW(r) (((((r) >> 3) & 1) << 2) | ((r) & 3))
__global__ __launch_bounds__(256, 4) void flash_attn(
    const u16* __restrict__ Qg, const u16* __restrict__ Kg,
    const u16* __restrict__ Vtg, u16* __restrict__ ctx) {
  __shared__ uint4 smem4[2208];              // 35328 B
  u16* S = (u16*)smem4;                      // buf b at +b*8192: K [64 key][64 d] (4096 u16,
                                             //   chunk c^=KSW(key)), V^T [64 d][64 key] at
                                             //   +4096 (chunk c^=(d&7))
  float* Of = (float*)smem4;                 // epilogue overlay: 2 x [64][68] f32 = 34816 B
  float* Lf = (float*)smem4 + 2*64*68;       // 128 f32 -> 35328 B total

  const int tid = threadIdx.x;
  const int wave = tid >> 6, lane = tid & 63;
  const int quad = lane >> 4, l16 = lane & 15;
  const int wq = wave >> 1, wk = wave & 1;
  const int h = blockIdx.x, qt = blockIdx.y, b = blockIdx.z;

  // Q B-frags (B[n=qrow=l16][k=dim=quad*8+j]); one-time global load
  bf8 qf[2][2];
  {
    const u16* qp = Qg + (size_t)(b*2048 + qt*64 + wq*32)*1024 + h*64;
    #pragma unroll
    for (int qs = 0; qs < 2; qs++)
      #pragma unroll
      for (int kc = 0; kc < 2; kc++)
        qf[qs][kc] = *(const bf8*)(qp + (size_t)(qs*16 + l16)*1024 + kc*32 + quad*8);
  }

  const f4 zz = {0.f, 0.f, 0.f, 0.f};
  f4 ot[4][2];                 // O^T acc: [d-sub][q-sub], elem (row=d=quad*4+r, col=qrow=l16)
  float lrow[2] = {0.f, 0.f};  // per-lane denominator partial
  #pragma unroll
  for (int ds = 0; ds < 4; ds++)
    #pragma unroll
    for (int qs = 0; qs < 2; qs++) ot[ds][qs] = zz;

  // staging bases (global side carries the XOR chunk-swizzle; LDS side linear).
  // K: thread covers key-row kr (+32p), chunk (tid&7)^KSW(kr); KSW invariant under +32.
  // V: thread covers d-row vd (+32p), chunk (tid&7)^(vd&7); invariant under +32.
  const int kr = tid >> 3;
  const u16* kga = Kg + (size_t)(b*2048 + kr)*1024 + h*64 + ((tid & 7) ^ KSW(kr))*8;
  const int vd = tid >> 3;
  const u16* vga = Vtg + (size_t)(h*64 + vd)*4096 + b*2048 + ((tid & 7) ^ (vd & 7))*8;

  // permuted K-row bases for the two QK frags (f=0,1): within the wave's 32-key block,
  // frag f, lane (quad,l16) reads key-row (l16>>2)*8 + f*4 + (l16&3).
  const int prow0 = ((l16 >> 2) << 3) + (l16 & 3);      // f=0
  const int prow1 = prow0 + 4;                           // f=1
  const int ksw   = (((l16 >> 2) & 1) << 2) | (l16 & 3); // = KSW(row) for this lane's rows

  // prologue: issue tile 0 into buf 0 (4 DMA calls/thread: 2 K passes + 2 V passes)
  #pragma unroll
  for (int p = 0; p < 2; p++) ASYNC16(kga + (size_t)(p*32)*1024, S + tid*8 + p*2048);
  #pragma unroll
  for (int p = 0; p < 2; p++) ASYNC16(vga + (size_t)(p*32)*4096, S + 4096 + tid*8 + p*2048);

  for (int t = 0; t < 32; t++) {
    const u16* Ks = S + (t & 1)*8192;
    const u16* Vt = Ks + 4096;
    if (t < 31) {
      // issue tile t+1 into the other buffer (its prior contents were read-complete at the
      // previous iteration's tail barrier)
      u16* kd = S + ((t + 1) & 1)*8192 + tid*8;
      const int kv1 = (t + 1)*64;
      #pragma unroll
      for (int p = 0; p < 2; p++) ASYNC16(kga + (size_t)(kv1 + p*32)*1024, kd + p*2048);
      #pragma unroll
      for (int p = 0; p < 2; p++) ASYNC16(vga + (size_t)(p*32)*4096 + kv1, kd + 4096 + p*2048);
      asm volatile("s_waitcnt vmcnt(4)" ::: "memory");   // tile t's 4 loads landed (FIFO)
    } else {
      asm volatile("s_waitcnt vmcnt(0)" ::: "memory");   // last tile: full drain
    }
    __builtin_amdgcn_sched_barrier(0);
    __builtin_amdgcn_s_barrier();    // tile t visible to all waves

    // --- S^T = K @ Q^T, keys permuted so output is PV-operand-local ---
    f4 st[2][2];                 // [f][qs]: scores for keys quad*8 + f*4 + r
    #pragma unroll
    for (int f = 0; f < 2; f++)
      #pragma unroll
      for (int qs = 0; qs < 2; qs++) st[f][qs] = zz;
    __builtin_amdgcn_s_setprio(1);
    #pragma unroll
    for (int f = 0; f < 2; f++) {
      const int row = wk*32 + (f ? prow1 : prow0);
      #pragma unroll
      for (int kc = 0; kc < 2; kc++) {
        bf8 kf = *(const bf8*)(Ks + row*64 + (((kc*4 + quad) ^ ksw)*8));
        #pragma unroll
        for (int qs = 0; qs < 2; qs++)
          st[f][qs] = __builtin_amdgcn_mfma_f32_16x16x32_bf16(kf, qf[qs][kc], st[f][qs], 0, 0, 0);
      }
    }
    __builtin_amdgcn_s_setprio(0);
    // --- exp2, per-lane row-sum, cvt_pk straight into the PV B-frag ---
    bf8 pf[2];
    #pragma unroll
    for (int qs = 0; qs < 2; qs++) {
      float p0 = fexp2(st[0][qs][0]), p1 = fexp2(st[0][qs][1]);
      float p2 = fexp2(st[0][qs][2]), p3 = fexp2(st[0][qs][3]);
      float p4 = fexp2(st[1][qs][0]), p5 = fexp2(st[1][qs][1]);
      float p6 = fexp2(st[1][qs][2]), p7 = fexp2(st[1][qs][3]);
      lrow[qs] += ((p0 + p1) + (p2 + p3)) + ((p4 + p5) + (p6 + p7));
      union { uint4 u; bf8 v; } pu;
      pu.u.x = pkbf(p0, p1);     // keys quad*8 + 0,1
      pu.u.y = pkbf(p2, p3);     // keys quad*8 + 2,3
      pu.u.z = pkbf(p4, p5);     // keys quad*8 + 4,5
      pu.u.w = pkbf(p6, p7);     // keys quad*8 + 6,7
      pf[qs] = pu.v;
    }
    // --- O^T += V^T-frag @ P ---
    __builtin_amdgcn_s_setprio(1);
    #pragma unroll
    for (int ds = 0; ds < 4; ds++) {
      const int d = ds*16 + l16;
      bf8 vf = *(const bf8*)(Vt + d*64 + (((wk*4 + quad) ^ (l16 & 7))*8));
      #pragma unroll
      for (int qs = 0; qs < 2; qs++)
        ot[ds][qs] = __builtin_amdgcn_mfma_f32_16x16x32_bf16(vf, pf[qs], ot[ds][qs], 0, 0, 0);
    }
    __builtin_amdgcn_s_setprio(0);

    // reads of buf[t] are data-complete (each ds_read's consumer MFMA executed above);
    // tail barrier before next iteration's DMA may overwrite this buffer
    asm volatile("s_waitcnt lgkmcnt(0)" ::: "memory");
    __builtin_amdgcn_s_barrier();
  }

  // ---------------- epilogue: reduce key-stripes, transpose, normalize, store ----------------
  __syncthreads();                 // everyone done with K/V bufs -> safe to overlay
  #pragma unroll
  for (int qs = 0; qs < 2; qs++) {
    lrow[qs] += __shfl_xor(lrow[qs], 16);
    lrow[qs] += __shfl_xor(lrow[qs], 32);
  }
  float* Ofw = Of + wk*(64*68);
  #pragma unroll
  for (int ds = 0; ds < 4; ds++)
    #pragma unroll
    for (int qs = 0; qs < 2; qs++)
      #pragma unroll
      for (int r = 0; r < 4; r++)
        Ofw[(wq*32 + qs*16 + l16)*68 + ds*16 + quad*4 + r] = ot[ds][qs][r];
  if (quad == 0) {
    Lf[wk*64 + wq*32 + l16]      = lrow[0];
    Lf[wk*64 + wq*32 + 16 + l16] = lrow[1];
  }
  __syncthreads();
  {
    const int qr = tid >> 2, dp = (tid & 3)*16;
    const float inv = 1.f / (Lf[qr] + Lf[64 + qr]);
    const float* o0 = Of + qr*68 + dp;
    const float* o1 = o0 + 64*68;
    unsigned ow[8];
    #pragma unroll
    for (int i = 0; i < 8; i++)
      ow[i] = pkbf((o0[2*i] + o1[2*i]) * inv, (o0[2*i+1] + o1[2*i+1]) * inv);
    u16* cp = ctx + (size_t)(b*2048 + qt*64 + qr)*1024 + h*64 + dp;
    *(uint4*)cp       = *(uint4*)&ow[0];
    *(uint4*)(cp + 8) = *(uint4*)&ow[4];
  }
}

extern "C" void kernel_launch(void* const* d_in, const int* in_sizes, int n_in,
                              void* d_out, int out_size, void* d_ws, size_t ws_size,
                              hipStream_t stream) {
  const float* key_  = (const float*)d_in[0];
  const float* query = (const float*)d_in[1];
  const float* value = (const float*)d_in[2];
  const float* Wq = (const float*)d_in[3];
  const float* Wk = (const float*)d_in[4];
  const float* Wv = (const float*)d_in[5];
  const float* Wo = (const float*)d_in[6];
  const float* bo = (const float*)d_in[7];
  float* out = (float*)d_out;

  u16* ws  = (u16*)d_ws;                 // needs 67.1 MB of workspace
  u16* xkb = ws;
  u16* xqb = ws + 4194304;
  u16* xvb = ws + 8388608;
  u16* Wqb = ws + 12582912;
  u16* Wkb = ws + 13631488;
  u16* Wvb = ws + 14680064;
  u16* Wob = ws + 15728640;
  u16* Qb  = ws + 16777216;              // Q (pre-scaled by 0.125*log2e) [4096,1024] bf16
  u16* Kb  = ws + 20971520;              // K [4096,1024] bf16
  u16* Vtb = ws + 25165824;              // V^T [1024,4096] bf16
  u16* Cb  = ws + 29360128;              // attention context [4096,1024] bf16

  cvt_all<<<8192, 256, 0, stream>>>(key_, query, value, Wq, Wk, Wv, Wo, ws);
  gemm_qkv<<<dim3(32, 8, 3), 256, 0, stream>>>(xqb, xkb, xvb, Wqb, Wkb, Wvb, Qb, Kb, Vtb);
  flash_attn<<<dim3(16, 32, 2), 256, 0, stream>>>(Qb, Kb, Vtb, Cb);
  gemm_out<<<dim3(64, 8), 256, 0, stream>>>(Cb, Wob, bo, out);
}